// Round 1
// baseline (713.864 us; speedup 1.0000x reference)
//
#include <hip/hip_runtime.h>
#include <hip/hip_bf16.h>

#define B_ 2
#define T_ 2048
#define DM_ 2048
#define H_ 16
#define KV_ 4
#define HD_ 128
#define M_ 4096   // B_*T_

typedef __attribute__((ext_vector_type(8))) short bf16x8;
typedef __attribute__((ext_vector_type(4))) float f32x4;
typedef __attribute__((ext_vector_type(4))) short s16x4;
typedef unsigned short u16;
typedef __attribute__((address_space(1))) unsigned int as1_u32;
typedef __attribute__((address_space(3))) unsigned int as3_u32;

__device__ inline u16 f2b(float f){
  __hip_bfloat16 h = __float2bfloat16(f);
  return *reinterpret_cast<u16*>(&h);
}
__device__ inline float b2f(u16 u){
  __hip_bfloat16 h = *reinterpret_cast<__hip_bfloat16*>(&u);
  return __bfloat162float(h);
}
__device__ inline f32x4 mfma16(bf16x8 a, bf16x8 b, f32x4 c){
  return __builtin_amdgcn_mfma_f32_16x16x32_bf16(a, b, c, 0, 0, 0);
}

// ---------------- fp32 -> bf16 convert (vectorized) ----------------
__global__ void cvt_f32_bf16(const float* __restrict__ in, u16* __restrict__ out){
  int i = (blockIdx.x*256 + threadIdx.x)*4;
  float4 v = *reinterpret_cast<const float4*>(in + i);
  s16x4 o;
  o[0] = (short)f2b(v.x); o[1] = (short)f2b(v.y);
  o[2] = (short)f2b(v.z); o[3] = (short)f2b(v.w);
  *reinterpret_cast<s16x4*>(out + i) = o;
}

// ------------- W [K][N] fp32  ->  Wt [N][K] bf16 (LDS tiled) -------------
__global__ void transpose_cvt(const float* __restrict__ W, u16* __restrict__ Wt, int K, int N){
  __shared__ float tile[32][33];
  const int n0 = blockIdx.x*32, k0 = blockIdx.y*32;
  const int tx = threadIdx.x, ty = threadIdx.y;
#pragma unroll
  for (int i=0;i<4;i++)
    tile[ty+8*i][tx] = W[(size_t)(k0+ty+8*i)*N + n0 + tx];
  __syncthreads();
#pragma unroll
  for (int i=0;i<4;i++)
    Wt[(size_t)(n0+ty+8*i)*K + k0 + tx] = f2b(tile[tx][ty+8*i]);
}

// ------------- vb [b*T+t][KV*HD] bf16 -> vt [(b*KV+kv)*HD + d][T] bf16 -------------
__global__ void transpose_v(const u16* __restrict__ vb, u16* __restrict__ vt){
  __shared__ u16 tile[32][33];
  const int t0 = blockIdx.x*32, d0 = blockIdx.y*32, bk = blockIdx.z;
  const int bb = bk >> 2, kv = bk & 3;
  const int tx = threadIdx.x, ty = threadIdx.y;
#pragma unroll
  for (int i=0;i<4;i++)
    tile[ty+8*i][tx] = vb[(size_t)(bb*T_ + t0+ty+8*i)*(KV_*HD_) + kv*HD_ + d0 + tx];
  __syncthreads();
#pragma unroll
  for (int i=0;i<4;i++)
    vt[(size_t)(bk*HD_ + d0+ty+8*i)*T_ + t0 + tx] = tile[tx][ty+8*i];
}

// ---------------- in-place RoPE on bf16 [M_][nh*HD] ----------------
__global__ void rope_kernel(u16* __restrict__ qk, int lognh){
  int idx = blockIdx.x*256 + threadIdx.x;
  int d  = idx & 63;
  int rh = idx >> 6;
  int nh = 1 << lognh;
  int h   = rh & (nh-1);
  int row = rh >> lognh;
  if (row >= M_) return;
  int t = row & (T_-1);
  // inv_freq = 10000^(-d/64) = exp2(-d * log2(10000)/64)
  float inv = exp2f((float)d * -0.2076205059304601f);
  float f = (float)t * inv;
  float sn, cs;
  sincosf(f, &sn, &cs);
  size_t base = ((size_t)row*nh + h)*HD_ + d;
  float a = b2f(qk[base]), b = b2f(qk[base+64]);
  qk[base]    = f2b(a*cs - b*sn);
  qk[base+64] = f2b(b*cs + a*sn);
}

// ---------------- bf16 GEMM: C[M][N] = A[M][K] * BT[N][K]^T ----------------
// m97 structure: 128x128 tile, 4 waves (2x2 of 64x64), BK=32, global_load_lds w=16.
__device__ inline void cstore(float* p, float v){ *p = v; }
__device__ inline void cstore(u16* p, float v){ *p = f2b(v); }

template<typename CT>
__global__ __launch_bounds__(256) void gemm_bt(const u16* __restrict__ A, const u16* __restrict__ BT,
                                               CT* __restrict__ C, int M, int N, int K)
{
  __shared__ u16 Als[128*32];
  __shared__ u16 Bls[128*32];
  const int tid = threadIdx.x;
  const int wave = tid>>6, lane = tid&63;
  const int m0 = blockIdx.y*128, n0 = blockIdx.x*128;
  const int wr = (wave>>1)*64, wc = (wave&1)*64;

  f32x4 acc[4][4];
#pragma unroll
  for (int i=0;i<4;i++)
#pragma unroll
    for (int j=0;j<4;j++) acc[i][j] = f32x4{0.f,0.f,0.f,0.f};

  // staging geometry: call c in {0,1}: linear elem = ((wave*2+c)*64+lane)*8
  const int lin0 = ((wave*2+0)*64 + lane)*8;
  const int lin1 = ((wave*2+1)*64 + lane)*8;
  const int r0 = lin0>>5, c0 = lin0&31;
  const int r1 = lin1>>5, c1 = lin1&31;

  for (int k0=0; k0<K; k0+=32){
    __syncthreads();
    __builtin_amdgcn_global_load_lds((as1_u32*)(A  + (size_t)(m0+r0)*K + k0 + c0),
                                     (as3_u32*)(Als + (wave*2+0)*512), 16, 0, 0);
    __builtin_amdgcn_global_load_lds((as1_u32*)(A  + (size_t)(m0+r1)*K + k0 + c1),
                                     (as3_u32*)(Als + (wave*2+1)*512), 16, 0, 0);
    __builtin_amdgcn_global_load_lds((as1_u32*)(BT + (size_t)(n0+r0)*K + k0 + c0),
                                     (as3_u32*)(Bls + (wave*2+0)*512), 16, 0, 0);
    __builtin_amdgcn_global_load_lds((as1_u32*)(BT + (size_t)(n0+r1)*K + k0 + c1),
                                     (as3_u32*)(Bls + (wave*2+1)*512), 16, 0, 0);
    __syncthreads();

    bf16x8 af[4], bfr[4];
#pragma unroll
    for (int mi=0;mi<4;mi++)
      af[mi] = *reinterpret_cast<const bf16x8*>(Als + (wr + mi*16 + (lane&15))*32 + 8*(lane>>4));
#pragma unroll
    for (int ni=0;ni<4;ni++)
      bfr[ni] = *reinterpret_cast<const bf16x8*>(Bls + (wc + ni*16 + (lane&15))*32 + 8*(lane>>4));
#pragma unroll
    for (int mi=0;mi<4;mi++)
#pragma unroll
      for (int ni=0;ni<4;ni++)
        acc[mi][ni] = mfma16(af[mi], bfr[ni], acc[mi][ni]);
  }

#pragma unroll
  for (int mi=0;mi<4;mi++)
#pragma unroll
    for (int ni=0;ni<4;ni++)
#pragma unroll
      for (int j=0;j<4;j++){
        int row = m0 + wr + mi*16 + (lane>>4)*4 + j;
        int col = n0 + wc + ni*16 + (lane&15);
        cstore(C + (size_t)row*N + col, acc[mi][ni][j]);
      }
}

// ---------------- causal GQA flash attention ----------------
// 1 wave = 16 q rows of one (b,h). S^T = K·Q^T via mfma(K,Q); softmax in-register;
// P through per-wave LDS (D-layout -> A-layout); PV with V^T global fragments.
__global__ __launch_bounds__(256) void attn_kernel(const u16* __restrict__ Qb, const u16* __restrict__ Kb,
                                                   const u16* __restrict__ Vt, u16* __restrict__ Oa)
{
  __shared__ u16 plds[4][16*40];   // per-wave P buffer, row stride 40 (80B, 16B-aligned)
  const int wave = threadIdx.x>>6, lane = threadIdx.x&63;
  const int g = lane>>4, qc = lane&15;
  const int qtg = blockIdx.x*4 + wave;        // global q-tile id
  const int qt = qtg & 127;                   // T/16 = 128 tiles per (b,h)
  const int bh = qtg >> 7;
  const int h = bh & (H_-1);
  const int b = bh >> 4;
  const int kv = h >> 2;                      // NREP = 4

  const u16* qrow = Qb + (size_t)(b*T_ + qt*16 + qc)*(H_*HD_) + h*HD_ + 8*g;
  bf16x8 qf[4];
#pragma unroll
  for (int d4=0; d4<4; d4++)
    qf[d4] = *reinterpret_cast<const bf16x8*>(qrow + d4*32);

  const u16* kbase = Kb + (size_t)(b*T_)*(KV_*HD_) + kv*HD_ + 8*g;
  const u16* vbase = Vt + (size_t)(b*KV_+kv)*HD_*T_;

  f32x4 oacc[8];
#pragma unroll
  for (int i=0;i<8;i++) oacc[i] = f32x4{0.f,0.f,0.f,0.f};
  float mrun = -1e30f, lrun = 0.f;
  const float SCALE = 0.08838834764831845f;   // 1/sqrt(128)
  const float L2E = 1.4426950408889634f;
  const int qglob = qt*16 + qc;
  const int send = qt*16 + 16;
  u16* pw = &plds[wave][0];

  for (int s0=0; s0<send; s0+=32){
    f32x4 s_a = f32x4{0.f,0.f,0.f,0.f}, s_b = f32x4{0.f,0.f,0.f,0.f};
#pragma unroll
    for (int d4=0; d4<4; d4++){
      bf16x8 kf0 = *reinterpret_cast<const bf16x8*>(kbase + (size_t)(s0 + qc)*(KV_*HD_) + d4*32);
      bf16x8 kf1 = *reinterpret_cast<const bf16x8*>(kbase + (size_t)(s0 + 16 + qc)*(KV_*HD_) + d4*32);
      s_a = mfma16(kf0, qf[d4], s_a);   // S^T tile0: row=s_local=(g*4+j), col=q=qc
      s_b = mfma16(kf1, qf[d4], s_b);   // S^T tile1
    }
    // mask + online softmax (per q = qc; lane holds 8 s-values)
    float p[8];
    float tmax = -1e30f;
#pragma unroll
    for (int u=0;u<2;u++)
#pragma unroll
      for (int j=0;j<4;j++){
        float v = (u ? s_b[j] : s_a[j]) * SCALE;
        int sg = s0 + u*16 + g*4 + j;
        v = (sg <= qglob) ? v : -1e30f;
        p[u*4+j] = v;
        tmax = fmaxf(tmax, v);
      }
    tmax = fmaxf(tmax, __shfl_xor(tmax, 16));
    tmax = fmaxf(tmax, __shfl_xor(tmax, 32));
    float mnew = fmaxf(mrun, tmax);
    float alpha = exp2f((mrun - mnew)*L2E);
    float rsum = 0.f;
#pragma unroll
    for (int i=0;i<8;i++){ p[i] = exp2f((p[i]-mnew)*L2E); rsum += p[i]; }
    rsum += __shfl_xor(rsum, 16);
    rsum += __shfl_xor(rsum, 32);
    lrun = lrun*alpha + rsum;
    mrun = mnew;
    // rescale O accumulator: O rows are q'=(g*4+j), alpha lives in lane q' (lanes 0..15)
    float aj[4];
#pragma unroll
    for (int j=0;j<4;j++) aj[j] = __shfl(alpha, g*4+j);
#pragma unroll
    for (int dt=0;dt<8;dt++)
#pragma unroll
      for (int j=0;j<4;j++) oacc[dt][j] *= aj[j];
    // write P to LDS as [q][s] (q=qc fixed per lane, s = u*16+g*4+j), packed b32
#pragma unroll
    for (int u=0;u<2;u++){
      unsigned w0 = (unsigned)f2b(p[u*4+0]) | ((unsigned)f2b(p[u*4+1])<<16);
      unsigned w1 = (unsigned)f2b(p[u*4+2]) | ((unsigned)f2b(p[u*4+3])<<16);
      *reinterpret_cast<unsigned*>(pw + qc*40 + u*16 + g*4)     = w0;
      *reinterpret_cast<unsigned*>(pw + qc*40 + u*16 + g*4 + 2) = w1;
    }
    // A-fragment: P[q=qc][s = 8g..8g+7] (wave-internal LDS, compiler orders lgkmcnt)
    bf16x8 pf = *reinterpret_cast<const bf16x8*>(pw + qc*40 + 8*g);
#pragma unroll
    for (int dt=0;dt<8;dt++){
      bf16x8 vf = *reinterpret_cast<const bf16x8*>(vbase + (size_t)(dt*16 + qc)*T_ + s0 + 8*g);
      oacc[dt] = mfma16(pf, vf, oacc[dt]);   // O[q'][d], row q'=(g*4+j), col d=dt*16+qc
    }
  }
  float linv = 1.f/lrun;
  float lj[4];
#pragma unroll
  for (int j=0;j<4;j++) lj[j] = __shfl(linv, g*4+j);
  u16* ob = Oa + (size_t)(b*T_ + qt*16)*(H_*HD_) + h*HD_;
#pragma unroll
  for (int dt=0;dt<8;dt++)
#pragma unroll
    for (int j=0;j<4;j++)
      ob[(size_t)(g*4+j)*(H_*HD_) + dt*16 + qc] = f2b(oacc[dt][j]*lj[j]);
}

// ---------------- launch ----------------
extern "C" void kernel_launch(void* const* d_in, const int* in_sizes, int n_in,
                              void* d_out, int out_size, void* d_ws, size_t ws_size,
                              hipStream_t stream)
{
  const float* x  = (const float*)d_in[0];
  const float* Wq = (const float*)d_in[1];
  const float* Wk = (const float*)d_in[2];
  const float* Wv = (const float*)d_in[3];
  const float* Wo = (const float*)d_in[4];
  float* out = (float*)d_out;

  char* ws = (char*)d_ws;
  size_t off = 0;
  auto carve = [&](size_t bytes)->void*{
    void* p = ws + off; off += (bytes + 255) & ~(size_t)255; return p;
  };
  u16* xb  = (u16*)carve((size_t)M_*DM_*2);
  u16* wqT = (u16*)carve((size_t)2048*2048*2);
  u16* wkT = (u16*)carve((size_t)512*2048*2);
  u16* wvT = (u16*)carve((size_t)512*2048*2);
  u16* woT = (u16*)carve((size_t)2048*2048*2);
  u16* qb  = (u16*)carve((size_t)M_*2048*2);
  u16* kb  = (u16*)carve((size_t)M_*512*2);
  u16* vb  = (u16*)carve((size_t)M_*512*2);
  u16* vt  = (u16*)carve((size_t)M_*512*2);
  u16* ao  = (u16*)carve((size_t)M_*2048*2);

  cvt_f32_bf16<<<8192, 256, 0, stream>>>(x, xb);
  transpose_cvt<<<dim3(64,64), dim3(32,8), 0, stream>>>(Wq, wqT, 2048, 2048);
  transpose_cvt<<<dim3(16,64), dim3(32,8), 0, stream>>>(Wk, wkT, 2048, 512);
  transpose_cvt<<<dim3(16,64), dim3(32,8), 0, stream>>>(Wv, wvT, 2048, 512);
  transpose_cvt<<<dim3(64,64), dim3(32,8), 0, stream>>>(Wo, woT, 2048, 2048);

  gemm_bt<u16><<<dim3(16,32), 256, 0, stream>>>(xb, wqT, qb, M_, 2048, 2048);
  gemm_bt<u16><<<dim3(4,32),  256, 0, stream>>>(xb, wkT, kb, M_, 512, 2048);
  gemm_bt<u16><<<dim3(4,32),  256, 0, stream>>>(xb, wvT, vb, M_, 512, 2048);

  rope_kernel<<<16384, 256, 0, stream>>>(qb, 4);  // 16 heads
  rope_kernel<<<4096,  256, 0, stream>>>(kb, 2);  // 4 heads

  transpose_v<<<dim3(64,4,8), dim3(32,8), 0, stream>>>(vb, vt);

  attn_kernel<<<1024, 256, 0, stream>>>(qb, kb, vt, ao);

  gemm_bt<float><<<dim3(16,32), 256, 0, stream>>>(ao, woT, out, M_, 2048, 2048);
}

// Round 2
// 355.732 us; speedup vs baseline: 2.0067x; 2.0067x over previous
//
#include <hip/hip_runtime.h>
#include <hip/hip_bf16.h>

#define B_ 2
#define T_ 2048
#define DM_ 2048
#define H_ 16
#define KV_ 4
#define HD_ 128
#define M_ 4096   // B_*T_

typedef __attribute__((ext_vector_type(8))) short bf16x8;
typedef __attribute__((ext_vector_type(4))) float f32x4;
typedef __attribute__((ext_vector_type(4))) short s16x4;
typedef unsigned short u16;
typedef __attribute__((address_space(1))) unsigned int as1_u32;
typedef __attribute__((address_space(3))) unsigned int as3_u32;

__device__ inline u16 f2b(float f){
  __hip_bfloat16 h = __float2bfloat16(f);
  return *reinterpret_cast<u16*>(&h);
}
__device__ inline float b2f(u16 u){
  __hip_bfloat16 h = *reinterpret_cast<__hip_bfloat16*>(&u);
  return __bfloat162float(h);
}
__device__ inline f32x4 mfma16(bf16x8 a, bf16x8 b, f32x4 c){
  return __builtin_amdgcn_mfma_f32_16x16x32_bf16(a, b, c, 0, 0, 0);
}

// ---------------- fp32 -> bf16 convert (vectorized) ----------------
__global__ void cvt_f32_bf16(const float* __restrict__ in, u16* __restrict__ out){
  int i = (blockIdx.x*256 + threadIdx.x)*4;
  float4 v = *reinterpret_cast<const float4*>(in + i);
  s16x4 o;
  o[0] = (short)f2b(v.x); o[1] = (short)f2b(v.y);
  o[2] = (short)f2b(v.z); o[3] = (short)f2b(v.w);
  *reinterpret_cast<s16x4*>(out + i) = o;
}

// ------------- W [K][N] fp32  ->  Wt [N][K] bf16 (LDS tiled) -------------
__global__ void transpose_cvt(const float* __restrict__ W, u16* __restrict__ Wt, int K, int N){
  __shared__ float tile[32][33];
  const int n0 = blockIdx.x*32, k0 = blockIdx.y*32;
  const int tx = threadIdx.x, ty = threadIdx.y;
#pragma unroll
  for (int i=0;i<4;i++)
    tile[ty+8*i][tx] = W[(size_t)(k0+ty+8*i)*N + n0 + tx];
  __syncthreads();
#pragma unroll
  for (int i=0;i<4;i++)
    Wt[(size_t)(n0+ty+8*i)*K + k0 + tx] = f2b(tile[tx][ty+8*i]);
}

// ------------- vb [b*T+t][KV*HD] bf16 -> vt [(b*KV+kv)*HD + d][T] bf16 -------------
__global__ void transpose_v(const u16* __restrict__ vb, u16* __restrict__ vt){
  __shared__ u16 tile[32][33];
  const int t0 = blockIdx.x*32, d0 = blockIdx.y*32, bk = blockIdx.z;
  const int bb = bk >> 2, kv = bk & 3;
  const int tx = threadIdx.x, ty = threadIdx.y;
#pragma unroll
  for (int i=0;i<4;i++)
    tile[ty+8*i][tx] = vb[(size_t)(bb*T_ + t0+ty+8*i)*(KV_*HD_) + kv*HD_ + d0 + tx];
  __syncthreads();
#pragma unroll
  for (int i=0;i<4;i++)
    vt[(size_t)(bk*HD_ + d0+ty+8*i)*T_ + t0 + tx] = tile[tx][ty+8*i];
}

// ---------------- in-place RoPE on bf16 [M_][nh*HD] ----------------
__global__ void rope_kernel(u16* __restrict__ qk, int lognh){
  int idx = blockIdx.x*256 + threadIdx.x;
  int d  = idx & 63;
  int rh = idx >> 6;
  int nh = 1 << lognh;
  int h   = rh & (nh-1);
  int row = rh >> lognh;
  if (row >= M_) return;
  int t = row & (T_-1);
  float inv = exp2f((float)d * -0.2076205059304601f);
  float f = (float)t * inv;
  float sn, cs;
  sincosf(f, &sn, &cs);
  size_t base = ((size_t)row*nh + h)*HD_ + d;
  float a = b2f(qk[base]), b = b2f(qk[base+64]);
  qk[base]    = f2b(a*cs - b*sn);
  qk[base+64] = f2b(b*cs + a*sn);
}

// ---------------- bf16 GEMM: C[M][N] = A[M][K] * BT[N][K]^T ----------------
__device__ inline void cstore(float* p, float v){ *p = v; }
__device__ inline void cstore(u16* p, float v){ *p = f2b(v); }

template<typename CT>
__global__ __launch_bounds__(256) void gemm_bt(const u16* __restrict__ A, const u16* __restrict__ BT,
                                               CT* __restrict__ C, int M, int N, int K)
{
  __shared__ u16 Als[128*32];
  __shared__ u16 Bls[128*32];
  const int tid = threadIdx.x;
  const int wave = tid>>6, lane = tid&63;
  // XCD-aware chunked swizzle (nwg % 8 == 0 for all our launches)
  const int gx = gridDim.x;
  int wid = blockIdx.y*gx + blockIdx.x;
  const int cpx = (gx*gridDim.y) >> 3;
  wid = (wid & 7)*cpx + (wid >> 3);
  const int m0 = (wid / gx)*128, n0 = (wid % gx)*128;
  const int wr = (wave>>1)*64, wc = (wave&1)*64;

  f32x4 acc[4][4];
#pragma unroll
  for (int i=0;i<4;i++)
#pragma unroll
    for (int j=0;j<4;j++) acc[i][j] = f32x4{0.f,0.f,0.f,0.f};

  const int lin0 = ((wave*2+0)*64 + lane)*8;
  const int lin1 = ((wave*2+1)*64 + lane)*8;
  const int r0 = lin0>>5, c0 = lin0&31;
  const int r1 = lin1>>5, c1 = lin1&31;

  for (int k0=0; k0<K; k0+=32){
    __syncthreads();
    __builtin_amdgcn_global_load_lds((as1_u32*)(A  + (size_t)(m0+r0)*K + k0 + c0),
                                     (as3_u32*)(Als + (wave*2+0)*512), 16, 0, 0);
    __builtin_amdgcn_global_load_lds((as1_u32*)(A  + (size_t)(m0+r1)*K + k0 + c1),
                                     (as3_u32*)(Als + (wave*2+1)*512), 16, 0, 0);
    __builtin_amdgcn_global_load_lds((as1_u32*)(BT + (size_t)(n0+r0)*K + k0 + c0),
                                     (as3_u32*)(Bls + (wave*2+0)*512), 16, 0, 0);
    __builtin_amdgcn_global_load_lds((as1_u32*)(BT + (size_t)(n0+r1)*K + k0 + c1),
                                     (as3_u32*)(Bls + (wave*2+1)*512), 16, 0, 0);
    __syncthreads();

    bf16x8 af[4], bfr[4];
#pragma unroll
    for (int mi=0;mi<4;mi++)
      af[mi] = *reinterpret_cast<const bf16x8*>(Als + (wr + mi*16 + (lane&15))*32 + 8*(lane>>4));
#pragma unroll
    for (int ni=0;ni<4;ni++)
      bfr[ni] = *reinterpret_cast<const bf16x8*>(Bls + (wc + ni*16 + (lane&15))*32 + 8*(lane>>4));
#pragma unroll
    for (int mi=0;mi<4;mi++)
#pragma unroll
      for (int ni=0;ni<4;ni++)
        acc[mi][ni] = mfma16(af[mi], bfr[ni], acc[mi][ni]);
  }

#pragma unroll
  for (int mi=0;mi<4;mi++)
#pragma unroll
    for (int ni=0;ni<4;ni++)
#pragma unroll
      for (int j=0;j<4;j++){
        int row = m0 + wr + mi*16 + (lane>>4)*4 + j;
        int col = n0 + wc + ni*16 + (lane&15);
        cstore(C + (size_t)row*N + col, acc[mi][ni][j]);
      }
}

// ---------------- causal GQA flash attention (v2) ----------------
// 1 wave = 32 q rows (QBLK=32) of one (b,h); KVBLK=32.
// S^T = mfma(K, Q); softmax in-register; P via per-wave LDS; PV with V^T global frags.
// K register double-buffer (kA/kB) + early V issue for latency hiding.
// Causal balance: block j owns tiles {2j, 63-2j, 2j+1, 62-2j}, rotated by j across waves.
__global__ __launch_bounds__(256, 2) void attn_kernel(const u16* __restrict__ Qb, const u16* __restrict__ Kb,
                                                      const u16* __restrict__ Vt, u16* __restrict__ Oa)
{
  __shared__ u16 plds[4][32*40];   // per-wave P buffer, row stride 40 u16 (80B, 16B-aligned)
  const int wave = threadIdx.x>>6, lane = threadIdx.x&63;
  const int g = lane>>4, qc = lane&15;
  const int j = blockIdx.x;        // 0..15
  const int bh = blockIdx.y;       // 0..31
  const int h = bh & (H_-1), b = bh >> 4;
  const int kv = h >> 2;

  // balanced tile set for this block; rotate assignment so co-resident blocks
  // don't put their heavy waves on the same SIMD
  int tset[4] = {2*j, 63-2*j, 2*j+1, 62-2*j};
  const int qt = tset[(wave + j) & 3];          // 32-row q-tile id, 0..63

  const u16* qbase = Qb + (size_t)(b*T_ + qt*32)*(H_*HD_) + h*HD_ + 8*g;
  bf16x8 qf[2][4];
#pragma unroll
  for (int qs=0; qs<2; qs++)
#pragma unroll
    for (int d4=0; d4<4; d4++)
      qf[qs][d4] = *reinterpret_cast<const bf16x8*>(qbase + (size_t)(qs*16+qc)*(H_*HD_) + d4*32);

  const u16* kbase = Kb + (size_t)(b*T_)*(KV_*HD_) + kv*HD_ + 8*g;
  const u16* vbase = Vt + (size_t)(b*KV_+kv)*HD_*T_ + 8*g;

  f32x4 oacc[2][8];
#pragma unroll
  for (int qs=0; qs<2; qs++)
#pragma unroll
    for (int dt=0; dt<8; dt++) oacc[qs][dt] = f32x4{0.f,0.f,0.f,0.f};
  float mrun[2] = {-1e30f, -1e30f};
  float lrun[2] = {0.f, 0.f};
  const float SCALE = 0.08838834764831845f;   // 1/sqrt(128)
  const float L2E = 1.4426950408889634f;
  u16* pw = &plds[wave][0];

  auto loadK = [&](bf16x8 (&kf)[8], int s0){
#pragma unroll
    for (int ss=0; ss<2; ss++)
#pragma unroll
      for (int d4=0; d4<4; d4++)
        kf[ss*4+d4] = *reinterpret_cast<const bf16x8*>(kbase + (size_t)(s0+ss*16+qc)*(KV_*HD_) + d4*32);
  };

  auto compute = [&](const bf16x8 (&kf)[8], int s0, bool masked){
    f32x4 sacc[2][2];
#pragma unroll
    for (int qs=0; qs<2; qs++)
#pragma unroll
      for (int ss=0; ss<2; ss++) sacc[qs][ss] = f32x4{0.f,0.f,0.f,0.f};
#pragma unroll
    for (int d4=0; d4<4; d4++)
#pragma unroll
      for (int ss=0; ss<2; ss++)
#pragma unroll
        for (int qs=0; qs<2; qs++)
          sacc[qs][ss] = mfma16(kf[ss*4+d4], qf[qs][d4], sacc[qs][ss]);

    // issue V loads early; consumed after softmax + LDS roundtrip
    bf16x8 vf[8];
#pragma unroll
    for (int dt=0; dt<8; dt++)
      vf[dt] = *reinterpret_cast<const bf16x8*>(vbase + (size_t)(dt*16+qc)*T_ + s0);

    float p[2][8], al[2], mnew[2];
#pragma unroll
    for (int qs=0; qs<2; qs++){
      float tm = -1e30f;
#pragma unroll
      for (int ss=0; ss<2; ss++)
#pragma unroll
        for (int jj=0; jj<4; jj++){
          float v = sacc[qs][ss][jj]*SCALE;
          if (masked){
            int sg = s0 + ss*16 + g*4 + jj;
            if (sg > qt*32 + qs*16 + qc) v = -1e30f;
          }
          p[qs][ss*4+jj] = v;
          tm = fmaxf(tm, v);
        }
      tm = fmaxf(tm, __shfl_xor(tm, 16));
      tm = fmaxf(tm, __shfl_xor(tm, 32));
      mnew[qs] = fmaxf(mrun[qs], tm);
      al[qs] = exp2f((mrun[qs]-mnew[qs])*L2E);
    }
#pragma unroll
    for (int qs=0; qs<2; qs++){
      float rs = 0.f;
#pragma unroll
      for (int i=0;i<8;i++){ p[qs][i] = exp2f((p[qs][i]-mnew[qs])*L2E); rs += p[qs][i]; }
      rs += __shfl_xor(rs, 16);
      rs += __shfl_xor(rs, 32);
      lrun[qs] = lrun[qs]*al[qs] + rs;
      mrun[qs] = mnew[qs];
    }
    // skip O-rescale when max didn't grow (alpha==1 exactly)
    if (!__all((al[0]==1.f) & (al[1]==1.f))){
      float aj0[4], aj1[4];
#pragma unroll
      for (int jj=0; jj<4; jj++){
        aj0[jj] = __shfl(al[0], g*4+jj);
        aj1[jj] = __shfl(al[1], g*4+jj);
      }
#pragma unroll
      for (int dt=0; dt<8; dt++)
#pragma unroll
        for (int jj=0; jj<4; jj++){
          oacc[0][dt][jj] *= aj0[jj];
          oacc[1][dt][jj] *= aj1[jj];
        }
    }
    // P -> LDS (D-layout) -> A-frags
#pragma unroll
    for (int qs=0; qs<2; qs++)
#pragma unroll
      for (int ss=0; ss<2; ss++){
        unsigned w0 = (unsigned)f2b(p[qs][ss*4+0]) | ((unsigned)f2b(p[qs][ss*4+1])<<16);
        unsigned w1 = (unsigned)f2b(p[qs][ss*4+2]) | ((unsigned)f2b(p[qs][ss*4+3])<<16);
        *reinterpret_cast<unsigned*>(pw + (qs*16+qc)*40 + ss*16 + g*4)     = w0;
        *reinterpret_cast<unsigned*>(pw + (qs*16+qc)*40 + ss*16 + g*4 + 2) = w1;
      }
    bf16x8 pf[2];
#pragma unroll
    for (int qs=0; qs<2; qs++)
      pf[qs] = *reinterpret_cast<const bf16x8*>(pw + (qs*16+qc)*40 + 8*g);
#pragma unroll
    for (int dt=0; dt<8; dt++)
#pragma unroll
      for (int qs=0; qs<2; qs++)
        oacc[qs][dt] = mfma16(pf[qs], vf[dt], oacc[qs][dt]);
  };

  // main loop: qt unmasked 32-s tiles + 1 masked diagonal tile, K reg-dbuf
  bf16x8 kA[8], kB[8];
  loadK(kA, 0);
  int s0 = 0, it = 0;
  const int n = qt;
  for (; it+2 <= n; it += 2, s0 += 64){
    loadK(kB, s0+32); compute(kA, s0, false);
    loadK(kA, s0+64); compute(kB, s0+32, false);
  }
  if (it < n){
    loadK(kB, s0+32);
    compute(kA, s0, false);
    compute(kB, s0+32, true);
  } else {
    compute(kA, s0, true);
  }

  float lj0[4], lj1[4];
  {
    float li0 = 1.f/lrun[0], li1 = 1.f/lrun[1];
#pragma unroll
    for (int jj=0; jj<4; jj++){
      lj0[jj] = __shfl(li0, g*4+jj);
      lj1[jj] = __shfl(li1, g*4+jj);
    }
  }
  u16* ob = Oa + (size_t)(b*T_ + qt*32)*(H_*HD_) + h*HD_;
#pragma unroll
  for (int dt=0; dt<8; dt++)
#pragma unroll
    for (int jj=0; jj<4; jj++){
      ob[(size_t)(0*16 + g*4+jj)*(H_*HD_) + dt*16 + qc] = f2b(oacc[0][dt][jj]*lj0[jj]);
      ob[(size_t)(1*16 + g*4+jj)*(H_*HD_) + dt*16 + qc] = f2b(oacc[1][dt][jj]*lj1[jj]);
    }
}

// ---------------- launch ----------------
extern "C" void kernel_launch(void* const* d_in, const int* in_sizes, int n_in,
                              void* d_out, int out_size, void* d_ws, size_t ws_size,
                              hipStream_t stream)
{
  const float* x  = (const float*)d_in[0];
  const float* Wq = (const float*)d_in[1];
  const float* Wk = (const float*)d_in[2];
  const float* Wv = (const float*)d_in[3];
  const float* Wo = (const float*)d_in[4];
  float* out = (float*)d_out;

  char* ws = (char*)d_ws;
  size_t off = 0;
  auto carve = [&](size_t bytes)->void*{
    void* p = ws + off; off += (bytes + 255) & ~(size_t)255; return p;
  };
  u16* xb  = (u16*)carve((size_t)M_*DM_*2);
  u16* wqT = (u16*)carve((size_t)2048*2048*2);
  u16* wkT = (u16*)carve((size_t)512*2048*2);
  u16* wvT = (u16*)carve((size_t)512*2048*2);
  u16* woT = (u16*)carve((size_t)2048*2048*2);
  u16* qb  = (u16*)carve((size_t)M_*2048*2);
  u16* kb  = (u16*)carve((size_t)M_*512*2);
  u16* vb  = (u16*)carve((size_t)M_*512*2);
  u16* vt  = (u16*)carve((size_t)M_*512*2);
  u16* ao  = (u16*)carve((size_t)M_*2048*2);

  cvt_f32_bf16<<<8192, 256, 0, stream>>>(x, xb);
  transpose_cvt<<<dim3(64,64), dim3(32,8), 0, stream>>>(Wq, wqT, 2048, 2048);
  transpose_cvt<<<dim3(16,64), dim3(32,8), 0, stream>>>(Wk, wkT, 2048, 512);
  transpose_cvt<<<dim3(16,64), dim3(32,8), 0, stream>>>(Wv, wvT, 2048, 512);
  transpose_cvt<<<dim3(64,64), dim3(32,8), 0, stream>>>(Wo, woT, 2048, 2048);

  gemm_bt<u16><<<dim3(16,32), 256, 0, stream>>>(xb, wqT, qb, M_, 2048, 2048);
  gemm_bt<u16><<<dim3(4,32),  256, 0, stream>>>(xb, wkT, kb, M_, 512, 2048);
  gemm_bt<u16><<<dim3(4,32),  256, 0, stream>>>(xb, wvT, vb, M_, 512, 2048);

  rope_kernel<<<16384, 256, 0, stream>>>(qb, 4);  // 16 heads
  rope_kernel<<<4096,  256, 0, stream>>>(kb, 2);  // 4 heads

  transpose_v<<<dim3(64,4,8), dim3(32,8), 0, stream>>>(vb, vt);

  attn_kernel<<<dim3(16,32), 256, 0, stream>>>(qb, kb, vt, ao);

  gemm_bt<float><<<dim3(16,32), 256, 0, stream>>>(ao, woT, out, M_, 2048, 2048);
}

// Round 3
// 301.457 us; speedup vs baseline: 2.3680x; 1.1800x over previous
//
#include <hip/hip_runtime.h>
#include <hip/hip_bf16.h>

#define B_ 2
#define T_ 2048
#define DM_ 2048
#define H_ 16
#define KV_ 4
#define HD_ 128
#define M_ 4096   // B_*T_
#define QKVN 3072 // H*HD + 2*KV*HD

typedef __attribute__((ext_vector_type(8))) short bf16x8;
typedef __attribute__((ext_vector_type(4))) float f32x4;
typedef __attribute__((ext_vector_type(4))) short s16x4;
typedef unsigned short u16;
typedef unsigned int u32;
typedef __attribute__((address_space(1))) unsigned int as1_u32;
typedef __attribute__((address_space(3))) unsigned int as3_u32;

__device__ inline u16 f2b(float f){
  __hip_bfloat16 h = __float2bfloat16(f);
  return *reinterpret_cast<u16*>(&h);
}
__device__ inline float b2f(u16 u){
  __hip_bfloat16 h = *reinterpret_cast<__hip_bfloat16*>(&u);
  return __bfloat162float(h);
}
__device__ inline f32x4 mfma16(bf16x8 a, bf16x8 b, f32x4 c){
  return __builtin_amdgcn_mfma_f32_16x16x32_bf16(a, b, c, 0, 0, 0);
}

// ---------------- fp32 -> bf16 convert (vectorized) ----------------
__global__ void cvt_f32_bf16(const float* __restrict__ in, u16* __restrict__ out){
  int i = (blockIdx.x*256 + threadIdx.x)*4;
  float4 v = *reinterpret_cast<const float4*>(in + i);
  s16x4 o;
  o[0] = (short)f2b(v.x); o[1] = (short)f2b(v.y);
  o[2] = (short)f2b(v.z); o[3] = (short)f2b(v.w);
  *reinterpret_cast<s16x4*>(out + i) = o;
}

// ------------- W [K][N] fp32  ->  Wt [N][K] bf16 (LDS tiled) -------------
__global__ void transpose_cvt(const float* __restrict__ W, u16* __restrict__ Wt, int K, int N){
  __shared__ float tile[32][33];
  const int n0 = blockIdx.x*32, k0 = blockIdx.y*32;
  const int tx = threadIdx.x, ty = threadIdx.y;
#pragma unroll
  for (int i=0;i<4;i++)
    tile[ty+8*i][tx] = W[(size_t)(k0+ty+8*i)*N + n0 + tx];
  __syncthreads();
#pragma unroll
  for (int i=0;i<4;i++)
    Wt[(size_t)(n0+ty+8*i)*K + k0 + tx] = f2b(tile[tx][ty+8*i]);
}

// ------------- V region of qkv [row][QKVN] -> vt [(b*KV+kv)*HD + d][T] -------------
__global__ void transpose_v(const u16* __restrict__ vb, u16* __restrict__ vt){
  __shared__ u16 tile[32][33];
  const int t0 = blockIdx.x*32, d0 = blockIdx.y*32, bk = blockIdx.z;
  const int bb = bk >> 2, kv = bk & 3;
  const int tx = threadIdx.x, ty = threadIdx.y;
#pragma unroll
  for (int i=0;i<4;i++)
    tile[ty+8*i][tx] = vb[(size_t)(bb*T_ + t0+ty+8*i)*QKVN + kv*HD_ + d0 + tx];
  __syncthreads();
#pragma unroll
  for (int i=0;i<4;i++)
    vt[(size_t)(bk*HD_ + d0+ty+8*i)*T_ + t0 + tx] = tile[tx][ty+8*i];
}

// ---------------- RoPE: table + vectorized apply ----------------
__global__ void rope_table(float2* __restrict__ tab){
  int idx = blockIdx.x*256 + threadIdx.x;   // t*64 + d, 131072 total
  int t = idx >> 6, d = idx & 63;
  float inv = exp2f((float)d * -0.2076205059304601f);  // 10000^(-d/64)
  float sn, cs;
  sincosf((float)t * inv, &sn, &cs);
  tab[idx] = float2{cs, sn};
}

__global__ void rope_apply(u16* __restrict__ qk, const float2* __restrict__ tab,
                           int lognh, int stride){
  int idx = blockIdx.x*256 + threadIdx.x;
  int dp = idx & 31;            // d pair: d = 2dp, 2dp+1
  int rh = idx >> 5;
  int nh = 1 << lognh;
  int h = rh & (nh-1);
  int row = rh >> lognh;
  if (row >= M_) return;
  int t = row & (T_-1);
  float4 cn = *reinterpret_cast<const float4*>(tab + t*64 + 2*dp); // cs0,sn0,cs1,sn1
  size_t base = (size_t)row*stride + h*HD_ + 2*dp;
  u32 lo = *reinterpret_cast<const u32*>(qk + base);
  u32 hi = *reinterpret_cast<const u32*>(qk + base + 64);
  float a0 = b2f(lo & 0xffff), a1 = b2f(lo >> 16);
  float b0 = b2f(hi & 0xffff), b1 = b2f(hi >> 16);
  u32 nlo = (u32)f2b(a0*cn.x - b0*cn.y) | ((u32)f2b(a1*cn.z - b1*cn.w) << 16);
  u32 nhi = (u32)f2b(b0*cn.x + a0*cn.y) | ((u32)f2b(b1*cn.z + a1*cn.w) << 16);
  *reinterpret_cast<u32*>(qk + base)      = nlo;
  *reinterpret_cast<u32*>(qk + base + 64) = nhi;
}

// ---------------- bf16 GEMM: C[M][N] = A[M][K] * BT[N][K]^T ----------------
__device__ inline void cstore(float* p, float v){ *p = v; }
__device__ inline void cstore(u16* p, float v){ *p = f2b(v); }

template<typename CT>
__global__ __launch_bounds__(256) void gemm_bt(const u16* __restrict__ A, const u16* __restrict__ BT,
                                               CT* __restrict__ C, int M, int N, int K)
{
  __shared__ u16 Als[128*32];
  __shared__ u16 Bls[128*32];
  const int tid = threadIdx.x;
  const int wave = tid>>6, lane = tid&63;
  const int gx = gridDim.x;
  int wid = blockIdx.y*gx + blockIdx.x;
  const int cpx = (gx*gridDim.y) >> 3;
  wid = (wid & 7)*cpx + (wid >> 3);
  const int m0 = (wid / gx)*128, n0 = (wid % gx)*128;
  const int wr = (wave>>1)*64, wc = (wave&1)*64;

  f32x4 acc[4][4];
#pragma unroll
  for (int i=0;i<4;i++)
#pragma unroll
    for (int j=0;j<4;j++) acc[i][j] = f32x4{0.f,0.f,0.f,0.f};

  const int lin0 = ((wave*2+0)*64 + lane)*8;
  const int lin1 = ((wave*2+1)*64 + lane)*8;
  const int r0 = lin0>>5, c0 = lin0&31;
  const int r1 = lin1>>5, c1 = lin1&31;

  for (int k0=0; k0<K; k0+=32){
    __syncthreads();
    __builtin_amdgcn_global_load_lds((as1_u32*)(A  + (size_t)(m0+r0)*K + k0 + c0),
                                     (as3_u32*)(Als + (wave*2+0)*512), 16, 0, 0);
    __builtin_amdgcn_global_load_lds((as1_u32*)(A  + (size_t)(m0+r1)*K + k0 + c1),
                                     (as3_u32*)(Als + (wave*2+1)*512), 16, 0, 0);
    __builtin_amdgcn_global_load_lds((as1_u32*)(BT + (size_t)(n0+r0)*K + k0 + c0),
                                     (as3_u32*)(Bls + (wave*2+0)*512), 16, 0, 0);
    __builtin_amdgcn_global_load_lds((as1_u32*)(BT + (size_t)(n0+r1)*K + k0 + c1),
                                     (as3_u32*)(Bls + (wave*2+1)*512), 16, 0, 0);
    __syncthreads();

    bf16x8 af[4], bfr[4];
#pragma unroll
    for (int mi=0;mi<4;mi++)
      af[mi] = *reinterpret_cast<const bf16x8*>(Als + (wr + mi*16 + (lane&15))*32 + 8*(lane>>4));
#pragma unroll
    for (int ni=0;ni<4;ni++)
      bfr[ni] = *reinterpret_cast<const bf16x8*>(Bls + (wc + ni*16 + (lane&15))*32 + 8*(lane>>4));
#pragma unroll
    for (int mi=0;mi<4;mi++)
#pragma unroll
      for (int ni=0;ni<4;ni++)
        acc[mi][ni] = mfma16(af[mi], bfr[ni], acc[mi][ni]);
  }

#pragma unroll
  for (int mi=0;mi<4;mi++)
#pragma unroll
    for (int ni=0;ni<4;ni++)
#pragma unroll
      for (int j=0;j<4;j++){
        int row = m0 + wr + mi*16 + (lane>>4)*4 + j;
        int col = n0 + wc + ni*16 + (lane&15);
        cstore(C + (size_t)row*N + col, acc[mi][ni][j]);
      }
}

// ---------------- causal GQA flash attention (v3: split-s flash-decode) ----------------
// Work unit = (bh, qt, chunk): chunk 0 = s-tiles [0, half), chunk 1 = [half, nt).
// Partial numerator (bf16) + (m,l) stats written; combine_kernel merges.
// Block j owns units {2j, 127-2j, 2j+1, 126-2j} (exactly 65 tiles/block), rotated by wave.
__global__ __launch_bounds__(256, 2) void attn_kernel(const u16* __restrict__ qkv,
                                                      const u16* __restrict__ Vt,
                                                      u16* __restrict__ Opart,
                                                      float* __restrict__ ml)
{
  __shared__ u16 plds[4][32*40];
  const int wave = threadIdx.x>>6, lane = threadIdx.x&63;
  const int g = lane>>4, qc = lane&15;
  const int jblk = blockIdx.x;     // 0..31
  const int bh = blockIdx.y;       // 0..31
  const int h = bh & (H_-1), b = bh >> 4;
  const int kv = h >> 2;

  int tset[4] = {2*jblk, 127-2*jblk, 2*jblk+1, 126-2*jblk};
  const int u = tset[(wave + jblk) & 3];
  const int qt = u >> 1, chunk = u & 1;
  const int nt = qt + 1;
  const int half = (nt + 1) >> 1;
  const int t_begin = chunk ? half : 0;
  const int t_end   = chunk ? nt : half;
  const int num = t_end - t_begin;

  const u16* qbase = qkv + (size_t)(b*T_ + qt*32)*QKVN + h*HD_ + 8*g;
  bf16x8 qf[2][4];
#pragma unroll
  for (int qs=0; qs<2; qs++)
#pragma unroll
    for (int d4=0; d4<4; d4++)
      qf[qs][d4] = *reinterpret_cast<const bf16x8*>(qbase + (size_t)(qs*16+qc)*QKVN + d4*32);

  const u16* kbase = qkv + (size_t)(b*T_)*QKVN + 2048 + kv*HD_ + 8*g;
  const u16* vbase = Vt + (size_t)(b*KV_+kv)*HD_*T_ + 8*g;

  f32x4 oacc[2][8];
#pragma unroll
  for (int qs=0; qs<2; qs++)
#pragma unroll
    for (int dt=0; dt<8; dt++) oacc[qs][dt] = f32x4{0.f,0.f,0.f,0.f};
  float mrun[2] = {-1e30f, -1e30f};
  float lrun[2] = {0.f, 0.f};
  const float SCALE = 0.08838834764831845f;
  const float L2E = 1.4426950408889634f;
  u16* pw = &plds[wave][0];

  auto loadK = [&](bf16x8 (&kf)[8], int s0){
#pragma unroll
    for (int ss=0; ss<2; ss++)
#pragma unroll
      for (int d4=0; d4<4; d4++)
        kf[ss*4+d4] = *reinterpret_cast<const bf16x8*>(kbase + (size_t)(s0+ss*16+qc)*QKVN + d4*32);
  };

  auto compute = [&](const bf16x8 (&kf)[8], int s0, bool masked){
    f32x4 sacc[2][2];
#pragma unroll
    for (int qs=0; qs<2; qs++)
#pragma unroll
      for (int ss=0; ss<2; ss++) sacc[qs][ss] = f32x4{0.f,0.f,0.f,0.f};
#pragma unroll
    for (int d4=0; d4<4; d4++)
#pragma unroll
      for (int ss=0; ss<2; ss++)
#pragma unroll
        for (int qs=0; qs<2; qs++)
          sacc[qs][ss] = mfma16(kf[ss*4+d4], qf[qs][d4], sacc[qs][ss]);

    bf16x8 vf[8];
#pragma unroll
    for (int dt=0; dt<8; dt++)
      vf[dt] = *reinterpret_cast<const bf16x8*>(vbase + (size_t)(dt*16+qc)*T_ + s0);

    float p[2][8], al[2], mnew[2];
#pragma unroll
    for (int qs=0; qs<2; qs++){
      float tm = -1e30f;
#pragma unroll
      for (int ss=0; ss<2; ss++)
#pragma unroll
        for (int jj=0; jj<4; jj++){
          float v = sacc[qs][ss][jj]*SCALE;
          if (masked){
            int sg = s0 + ss*16 + g*4 + jj;
            if (sg > qt*32 + qs*16 + qc) v = -1e30f;
          }
          p[qs][ss*4+jj] = v;
          tm = fmaxf(tm, v);
        }
      tm = fmaxf(tm, __shfl_xor(tm, 16));
      tm = fmaxf(tm, __shfl_xor(tm, 32));
      mnew[qs] = fmaxf(mrun[qs], tm);
      al[qs] = exp2f((mrun[qs]-mnew[qs])*L2E);
    }
#pragma unroll
    for (int qs=0; qs<2; qs++){
      float rs = 0.f;
#pragma unroll
      for (int i=0;i<8;i++){ p[qs][i] = exp2f((p[qs][i]-mnew[qs])*L2E); rs += p[qs][i]; }
      rs += __shfl_xor(rs, 16);
      rs += __shfl_xor(rs, 32);
      lrun[qs] = lrun[qs]*al[qs] + rs;
      mrun[qs] = mnew[qs];
    }
    if (!__all((al[0]==1.f) & (al[1]==1.f))){
      float aj0[4], aj1[4];
#pragma unroll
      for (int jj=0; jj<4; jj++){
        aj0[jj] = __shfl(al[0], g*4+jj);
        aj1[jj] = __shfl(al[1], g*4+jj);
      }
#pragma unroll
      for (int dt=0; dt<8; dt++)
#pragma unroll
        for (int jj=0; jj<4; jj++){
          oacc[0][dt][jj] *= aj0[jj];
          oacc[1][dt][jj] *= aj1[jj];
        }
    }
#pragma unroll
    for (int qs=0; qs<2; qs++)
#pragma unroll
      for (int ss=0; ss<2; ss++){
        unsigned w0 = (unsigned)f2b(p[qs][ss*4+0]) | ((unsigned)f2b(p[qs][ss*4+1])<<16);
        unsigned w1 = (unsigned)f2b(p[qs][ss*4+2]) | ((unsigned)f2b(p[qs][ss*4+3])<<16);
        *reinterpret_cast<unsigned*>(pw + (qs*16+qc)*40 + ss*16 + g*4)     = w0;
        *reinterpret_cast<unsigned*>(pw + (qs*16+qc)*40 + ss*16 + g*4 + 2) = w1;
      }
    bf16x8 pf[2];
#pragma unroll
    for (int qs=0; qs<2; qs++)
      pf[qs] = *reinterpret_cast<const bf16x8*>(pw + (qs*16+qc)*40 + 8*g);
#pragma unroll
    for (int dt=0; dt<8; dt++)
#pragma unroll
      for (int qs=0; qs<2; qs++)
        oacc[qs][dt] = mfma16(pf[qs], vf[dt], oacc[qs][dt]);
  };

  if (num > 0){
    bf16x8 kA[8], kB[8];
    int s = t_begin*32;
    loadK(kA, s);
    int i = 0;
    const bool lm = (t_end-1) == qt;   // diagonal (masked) tile is the chunk's last
    for (; i+2 < num; i+=2, s+=64){
      loadK(kB, s+32); compute(kA, s, false);
      loadK(kA, s+64); compute(kB, s+32, false);
    }
    if (num-i == 2){
      loadK(kB, s+32);
      compute(kA, s, false);
      compute(kB, s+32, lm);
    } else {
      compute(kA, s, lm);
    }
  }

  // write partial numerator (bf16) + stats
  const size_t unit = (size_t)(chunk*32 + bh)*64 + qt;
  u16* ob = Opart + unit*32*128;
#pragma unroll
  for (int qs=0; qs<2; qs++)
#pragma unroll
    for (int dt=0; dt<8; dt++)
#pragma unroll
      for (int jj=0; jj<4; jj++)
        ob[(size_t)(qs*16 + g*4+jj)*128 + dt*16 + qc] = f2b(oacc[qs][dt][jj]);
  if (lane < 16){
    float* mlb = ml + unit*64;
#pragma unroll
    for (int qs=0; qs<2; qs++){
      mlb[qs*16 + qc]      = mrun[qs];
      mlb[32 + qs*16 + qc] = lrun[qs];
    }
  }
}

// ---------------- combine partials -> attention output (bf16) ----------------
__global__ void combine_kernel(const u16* __restrict__ Opart, const float* __restrict__ ml,
                               u16* __restrict__ ao)
{
  const float L2E = 1.4426950408889634f;
  int idx = blockIdx.x*256 + threadIdx.x;   // 1,048,576 threads, 8 elems each
  int dg = idx & 15;
  int r  = (idx >> 4) & 31;
  int qt = (idx >> 9) & 63;
  int bh = idx >> 15;
  size_t u0 = (size_t)bh*64 + qt;
  size_t u1 = (size_t)(32 + bh)*64 + qt;
  float mA = ml[u0*64 + r],      lA = ml[u0*64 + 32 + r];
  float mB = ml[u1*64 + r],      lB = ml[u1*64 + 32 + r];
  float M  = fmaxf(mA, mB);
  float wA = exp2f((mA - M)*L2E);
  float wB = exp2f((mB - M)*L2E);
  float inv = 1.f / (wA*lA + wB*lB);
  bf16x8 a8 = *reinterpret_cast<const bf16x8*>(Opart + (u0*32 + r)*128 + dg*8);
  bf16x8 b8 = *reinterpret_cast<const bf16x8*>(Opart + (u1*32 + r)*128 + dg*8);
  bf16x8 o;
#pragma unroll
  for (int i=0;i<8;i++)
    o[i] = (short)f2b((wA*b2f((u16)a8[i]) + wB*b2f((u16)b8[i]))*inv);
  int b = bh >> 4, h = bh & 15;
  size_t row = (size_t)b*T_ + qt*32 + r;
  *reinterpret_cast<bf16x8*>(ao + row*2048 + h*128 + dg*8) = o;
}

// ---------------- launch ----------------
extern "C" void kernel_launch(void* const* d_in, const int* in_sizes, int n_in,
                              void* d_out, int out_size, void* d_ws, size_t ws_size,
                              hipStream_t stream)
{
  const float* x  = (const float*)d_in[0];
  const float* Wq = (const float*)d_in[1];
  const float* Wk = (const float*)d_in[2];
  const float* Wv = (const float*)d_in[3];
  const float* Wo = (const float*)d_in[4];
  float* out = (float*)d_out;

  char* ws = (char*)d_ws;
  size_t off = 0;
  auto carve = [&](size_t bytes)->void*{
    void* p = ws + off; off += (bytes + 255) & ~(size_t)255; return p;
  };
  u16*    xb   = (u16*)carve((size_t)M_*DM_*2);       // also reused as `ao` after QKV GEMM
  u16*    wT   = (u16*)carve((size_t)QKVN*2048*2);    // [Wq;Wk;Wv]^T
  u16*    woT  = (u16*)carve((size_t)2048*2048*2);
  u16*    qkv  = (u16*)carve((size_t)M_*QKVN*2);
  u16*    vt   = (u16*)carve((size_t)M_*512*2);
  float2* tab  = (float2*)carve((size_t)T_*64*8);
  float*  ml   = (float*)carve((size_t)2*32*64*64*4);
  u16*    ao   = xb;                                  // alias: xb dead after QKV GEMM
  u16*    part = (u16*)d_out;                         // 33.55 MB scratch, overwritten by final GEMM

  cvt_f32_bf16<<<8192, 256, 0, stream>>>(x, xb);
  rope_table<<<512, 256, 0, stream>>>(tab);
  transpose_cvt<<<dim3(64,64), dim3(32,8), 0, stream>>>(Wq, wT,               2048, 2048);
  transpose_cvt<<<dim3(16,64), dim3(32,8), 0, stream>>>(Wk, wT + 2048*2048,   2048, 512);
  transpose_cvt<<<dim3(16,64), dim3(32,8), 0, stream>>>(Wv, wT + 2560*2048,   2048, 512);
  transpose_cvt<<<dim3(64,64), dim3(32,8), 0, stream>>>(Wo, woT,              2048, 2048);

  gemm_bt<u16><<<dim3(24,32), 256, 0, stream>>>(xb, wT, qkv, M_, QKVN, 2048);

  rope_apply<<<8192, 256, 0, stream>>>(qkv,        tab, 4, QKVN);  // Q: 16 heads
  rope_apply<<<2048, 256, 0, stream>>>(qkv + 2048, tab, 2, QKVN);  // K: 4 heads

  transpose_v<<<dim3(64,4,8), dim3(32,8), 0, stream>>>(qkv + 2560, vt);

  attn_kernel<<<dim3(32,32), 256, 0, stream>>>(qkv, vt, part, ml);
  combine_kernel<<<4096, 256, 0, stream>>>(part, ml, ao);

  gemm_bt<float><<<dim3(16,32), 256, 0, stream>>>(ao, woT, out, M_, 2048, 2048);
}